// Round 3
// baseline (497.418 us; speedup 1.0000x reference)
//
#include <hip/hip_runtime.h>

// OrthogonalButterfly: 20 layers of Givens rotations on pairs (j, j+512)
// followed by a perfect shuffle (dest = rotl1(src) on the 10-bit index).
// In the substituted domain y_d[i] = x_d[rotl_d(i)] the network is an
// in-place butterfly: layer d pairs indices differing in bit b=9-(d%10),
// coefficient index j = rotl_{d%10}(i with bit b cleared). rotl^20 == id
// on 10 bits, so y_20 == x_20: no physical permutation anywhere.
//
// R1 lesson: layer constants must be compile-time (template<int d>), else y
// goes to scratch (rule #20).
// R2 lesson: VGPR=128 == sizeof(y) — the backend targeted 4 waves/EU and
// spilled ~60 regs (550MB extra writes). Fix: amdgpu_waves_per_eu(2,2) pins
// the occupancy target (cap 256 VGPR), plus per-pair coefficient loads so
// peak live coeffs = 2 regs not 32. Also move xor1/2/8 shuffles to DPP
// (VALU pipe) and xor4/16 to ds_swizzle, halving DS-pipe work.

#define WIDTH   1024
#define DEPTH   20
#define NROWS   32768
#define TILE    8          // rows per wave, held in registers (8*16 VGPR)

// ---------------------------------------------------------------------------
// Setup: bake per-(layer, reg, lane) coefficient pairs (cos, +-sin), sign
// folded per element, gathered into the exact order the main kernel reads.
// tab[(d*16 + r)*64 + lane] = (c, s_eff).  Size: 20*16*64*8 B = 160 KiB.
// (Unchanged from R2 — proven correct, absmax 0.0156.)
// ---------------------------------------------------------------------------
__global__ void bfly_setup(const float* __restrict__ params,
                           float2* __restrict__ tab) {
  int tid = blockIdx.x * blockDim.x + threadIdx.x;
  if (tid >= DEPTH * 16 * 64) return;
  int L = tid & 63;          // lane   = i[7:2]
  int r = (tid >> 6) & 15;   // reg    = {i[9:8], i[1:0]}
  int d = tid >> 10;         // layer
  int i = ((r >> 2) << 8) | (L << 2) | (r & 3);   // reconstruct element index
  int rot = d % 10;
  int b = 9 - rot;           // butterfly bit for this layer
  int m = 1 << b;
  int i0 = i & ~m;
  int j = rot ? (((i0 << rot) | (i0 >> (10 - rot))) & 1023) : i0;  // j < 512
  float theta = params[j * DEPTH + d];   // params is (512, 20) row-major
  float c = cosf(theta);
  float s = sinf(theta);
  if (i & m) s = -s;         // "x1" element: c*self - s*partner
  tab[(d * 16 + r) * 64 + L] = make_float2(c, s);
}

// ---------------------------------------------------------------------------
// Cross-lane partner fetch, compile-time mask.
//   xor1,2  -> DPP quad_perm            (VALU)
//   xor8    -> DPP row_ror:8 == xor8    (VALU)
//   xor4,16 -> ds_swizzle BitMode       (DS, conflict-free)
//   xor32   -> __shfl_xor               (DS)
// ---------------------------------------------------------------------------
template <int lm>
__device__ __forceinline__ float partner(float x) {
  if constexpr (lm == 1) {
    return __int_as_float(__builtin_amdgcn_update_dpp(
        0, __float_as_int(x), 0xB1, 0xF, 0xF, true));      // quad [1,0,3,2]
  } else if constexpr (lm == 2) {
    return __int_as_float(__builtin_amdgcn_update_dpp(
        0, __float_as_int(x), 0x4E, 0xF, 0xF, true));      // quad [2,3,0,1]
  } else if constexpr (lm == 8) {
    return __int_as_float(__builtin_amdgcn_update_dpp(
        0, __float_as_int(x), 0x128, 0xF, 0xF, true));     // row_ror:8 == xor8
  } else if constexpr (lm == 4) {
    return __int_as_float(__builtin_amdgcn_ds_swizzle(
        __float_as_int(x), 0x101F));                       // xor4, and=0x1F
  } else if constexpr (lm == 16) {
    return __int_as_float(__builtin_amdgcn_ds_swizzle(
        __float_as_int(x), 0x401F));                       // xor16, and=0x1F
  } else {
    return __shfl_xor(x, 32, 64);                          // xor32
  }
}

// ---------------------------------------------------------------------------
// One butterfly layer, all constants compile-time, minimal live coefficients.
// ---------------------------------------------------------------------------
template <int d>
__device__ __forceinline__ void bfly_layer(float (&y)[TILE][16],
                                           const float2* __restrict__ tab,
                                           int lane) {
  constexpr int b = 9 - (d % 10);

  if constexpr (b >= 8 || b <= 1) {
    // register-local pair: reg bit 3<->i9, 2<->i8, 1<->i1, 0<->i0
    constexpr int rm = (b == 9) ? 8 : (b == 8) ? 4 : (b == 1) ? 2 : 1;
#pragma unroll
    for (int r = 0; r < 16; ++r) {
      if ((r & rm) == 0) {              // folds at unroll (r, rm const)
        const int r2 = r | rm;
        // slot r holds (c, +s); pair member r2 uses (c, -s) -> explicit minus
        float2 cs = tab[(d * 16 + r) * 64 + lane];
#pragma unroll
        for (int t = 0; t < TILE; ++t) {
          float a0 = y[t][r];
          float a1 = y[t][r2];
          y[t][r]  = cs.x * a0 + cs.y * a1;
          y[t][r2] = cs.x * a1 - cs.y * a0;
        }
      }
    }
  } else {
    // cross-lane pair: lane bit (b-2); table s is sign-folded per lane
    constexpr int lm = 1 << (b - 2);
#pragma unroll
    for (int r = 0; r < 16; ++r) {
      float2 cs = tab[(d * 16 + r) * 64 + lane];
#pragma unroll
      for (int t = 0; t < TILE; ++t) {
        float p = partner<lm>(y[t][r]);
        y[t][r] = cs.x * y[t][r] + cs.y * p;
      }
    }
  }
}

// ---------------------------------------------------------------------------
// Main: one wave per 8 rows. Layout: lane = i[7:2], reg = {i[9:8], i[1:0]}
//  -> bits 9,8,1,0 are register-local pairs; bits 7..2 are cross-lane.
//  -> float4 global loads/stores (16 B/lane).
// waves_per_eu(2,2): y alone is 128 VGPR, so >=2 waves/EU is impossible
// anyway; pinning stops the allocator from spilling to chase 4 waves/EU.
// ---------------------------------------------------------------------------
__global__ __launch_bounds__(256)
__attribute__((amdgpu_waves_per_eu(2, 2)))
void bfly_main(const float* __restrict__ X,
               const float2* __restrict__ tab,
               float* __restrict__ out) {
  const int lane = threadIdx.x & 63;
  const int wid  = blockIdx.x * (blockDim.x >> 6) + (threadIdx.x >> 6);
  const long base = (long)wid * TILE * WIDTH;

  float y[TILE][16];

  // ---- load 8 rows, 4 float4 each ----
  const float* xp = X + base;
#pragma unroll
  for (int t = 0; t < TILE; ++t) {
#pragma unroll
    for (int k = 0; k < 4; ++k) {
      float4 v = *reinterpret_cast<const float4*>(
          xp + t * WIDTH + k * 256 + lane * 4);
      y[t][k * 4 + 0] = v.x;
      y[t][k * 4 + 1] = v.y;
      y[t][k * 4 + 2] = v.z;
      y[t][k * 4 + 3] = v.w;
    }
  }

  // ---- 20 layers, each a separate instantiation with constexpr constants --
  bfly_layer<0>(y, tab, lane);
  bfly_layer<1>(y, tab, lane);
  bfly_layer<2>(y, tab, lane);
  bfly_layer<3>(y, tab, lane);
  bfly_layer<4>(y, tab, lane);
  bfly_layer<5>(y, tab, lane);
  bfly_layer<6>(y, tab, lane);
  bfly_layer<7>(y, tab, lane);
  bfly_layer<8>(y, tab, lane);
  bfly_layer<9>(y, tab, lane);
  bfly_layer<10>(y, tab, lane);
  bfly_layer<11>(y, tab, lane);
  bfly_layer<12>(y, tab, lane);
  bfly_layer<13>(y, tab, lane);
  bfly_layer<14>(y, tab, lane);
  bfly_layer<15>(y, tab, lane);
  bfly_layer<16>(y, tab, lane);
  bfly_layer<17>(y, tab, lane);
  bfly_layer<18>(y, tab, lane);
  bfly_layer<19>(y, tab, lane);

  // ---- store (y_20 == x_20: no permutation) ----
  float* op = out + base;
#pragma unroll
  for (int t = 0; t < TILE; ++t) {
#pragma unroll
    for (int k = 0; k < 4; ++k) {
      float4 v;
      v.x = y[t][k * 4 + 0];
      v.y = y[t][k * 4 + 1];
      v.z = y[t][k * 4 + 2];
      v.w = y[t][k * 4 + 3];
      *reinterpret_cast<float4*>(op + t * WIDTH + k * 256 + lane * 4) = v;
    }
  }
}

extern "C" void kernel_launch(void* const* d_in, const int* in_sizes, int n_in,
                              void* d_out, int out_size, void* d_ws, size_t ws_size,
                              hipStream_t stream) {
  const float* X      = (const float*)d_in[0];
  const float* params = (const float*)d_in[1];
  float* out          = (float*)d_out;
  float2* tab         = (float2*)d_ws;   // needs 160 KiB of ws

  // 1) bake coefficient table (re-done every call; ws is re-poisoned)
  bfly_setup<<<(DEPTH * 16 * 64 + 255) / 256, 256, 0, stream>>>(params, tab);

  // 2) butterfly: 32768 rows / 8 rows-per-wave = 4096 waves = 1024 blocks
  bfly_main<<<(NROWS / TILE) / 4, 256, 0, stream>>>(X, tab, out);
}

// Round 11
// 271.728 us; speedup vs baseline: 1.8306x; 1.8306x over previous
//
#include <hip/hip_runtime.h>

// OrthogonalButterfly: 20 layers of Givens rotations on pairs (j, j+512)
// followed by a perfect shuffle (dest = rotl1(src) on the 10-bit index).
// In the substituted domain y_d[i] = x_d[rotl_d(i)] the network is an
// in-place butterfly: layer d pairs indices differing in bit b=9-(d%10),
// coefficient index j = rotl_{d%10}(i with bit b cleared). rotl^20 == id
// on 10 bits, so y_20 == x_20: no physical permutation anywhere.
//
// R1 lesson: layer constants must be compile-time (template<int d>), else y
// goes to scratch (rule #20).
// R2/R3 lesson: the allocator will NOT give more than 128 VGPR here
// (waves_per_eu(2,2) ignored; both rounds spilled 0.5-0.8 GB of scratch).
// Fix: fit 128 by construction — TILE=4 (y=64 regs) instead of 8. Occupancy
// doubles to 4 waves/EU, spills vanish; coefficient L2 traffic doubles but
// stays far below the HBM stream cost.
// R4-R10: infra failures (timeouts / container) — identical kernel, untested.

#define WIDTH   1024
#define DEPTH   20
#define NROWS   32768
#define TILE    4          // rows per wave, held in registers (4*16 VGPR)

// ---------------------------------------------------------------------------
// Setup: bake per-(layer, reg, lane) coefficient pairs (cos, +-sin), sign
// folded per element, gathered into the exact order the main kernel reads.
// tab[(d*16 + r)*64 + lane] = (c, s_eff).  Size: 20*16*64*8 B = 160 KiB.
// (Unchanged since R2 — proven correct, absmax 0.0156.)
// ---------------------------------------------------------------------------
__global__ void bfly_setup(const float* __restrict__ params,
                           float2* __restrict__ tab) {
  int tid = blockIdx.x * blockDim.x + threadIdx.x;
  if (tid >= DEPTH * 16 * 64) return;
  int L = tid & 63;          // lane   = i[7:2]
  int r = (tid >> 6) & 15;   // reg    = {i[9:8], i[1:0]}
  int d = tid >> 10;         // layer
  int i = ((r >> 2) << 8) | (L << 2) | (r & 3);   // reconstruct element index
  int rot = d % 10;
  int b = 9 - rot;           // butterfly bit for this layer
  int m = 1 << b;
  int i0 = i & ~m;
  int j = rot ? (((i0 << rot) | (i0 >> (10 - rot))) & 1023) : i0;  // j < 512
  float theta = params[j * DEPTH + d];   // params is (512, 20) row-major
  float c = cosf(theta);
  float s = sinf(theta);
  if (i & m) s = -s;         // "x1" element: c*self - s*partner
  tab[(d * 16 + r) * 64 + L] = make_float2(c, s);
}

// ---------------------------------------------------------------------------
// Cross-lane partner fetch, compile-time mask.
//   xor1,2  -> DPP quad_perm            (VALU)   [verified R3]
//   xor8    -> DPP row_ror:8 == xor8    (VALU)   [verified R3]
//   xor4,16 -> ds_swizzle BitMode       (DS, conflict-free)
//   xor32   -> __shfl_xor               (DS)
// ---------------------------------------------------------------------------
template <int lm>
__device__ __forceinline__ float partner(float x) {
  if constexpr (lm == 1) {
    return __int_as_float(__builtin_amdgcn_update_dpp(
        0, __float_as_int(x), 0xB1, 0xF, 0xF, true));      // quad [1,0,3,2]
  } else if constexpr (lm == 2) {
    return __int_as_float(__builtin_amdgcn_update_dpp(
        0, __float_as_int(x), 0x4E, 0xF, 0xF, true));      // quad [2,3,0,1]
  } else if constexpr (lm == 8) {
    return __int_as_float(__builtin_amdgcn_update_dpp(
        0, __float_as_int(x), 0x128, 0xF, 0xF, true));     // row_ror:8 == xor8
  } else if constexpr (lm == 4) {
    return __int_as_float(__builtin_amdgcn_ds_swizzle(
        __float_as_int(x), 0x101F));                       // xor4, and=0x1F
  } else if constexpr (lm == 16) {
    return __int_as_float(__builtin_amdgcn_ds_swizzle(
        __float_as_int(x), 0x401F));                       // xor16, and=0x1F
  } else {
    return __shfl_xor(x, 32, 64);                          // xor32
  }
}

// ---------------------------------------------------------------------------
// One butterfly layer, all constants compile-time. Batch-load the layer's
// 16 coefficient pairs first (independent loads issue together), then apply.
// ---------------------------------------------------------------------------
template <int d>
__device__ __forceinline__ void bfly_layer(float (&y)[TILE][16],
                                           const float2* __restrict__ tab,
                                           int lane) {
  constexpr int b = 9 - (d % 10);

  float2 cs[16];
#pragma unroll
  for (int r = 0; r < 16; ++r)
    cs[r] = tab[(d * 16 + r) * 64 + lane];

  if constexpr (b >= 8 || b <= 1) {
    // register-local pair: reg bit 3<->i9, 2<->i8, 1<->i1, 0<->i0
    constexpr int rm = (b == 9) ? 8 : (b == 8) ? 4 : (b == 1) ? 2 : 1;
#pragma unroll
    for (int r = 0; r < 16; ++r) {
      if ((r & rm) == 0) {              // folds at unroll (r, rm const)
        const int r2 = r | rm;
#pragma unroll
        for (int t = 0; t < TILE; ++t) {
          float a0 = y[t][r];
          float a1 = y[t][r2];
          y[t][r]  = cs[r].x * a0 + cs[r].y * a1;   // slot r holds (c, +s)
          y[t][r2] = cs[r].x * a1 - cs[r].y * a0;   // partner uses (c, -s)
        }
      }
    }
  } else {
    // cross-lane pair: lane bit (b-2); table s is sign-folded per lane
    constexpr int lm = 1 << (b - 2);
#pragma unroll
    for (int r = 0; r < 16; ++r) {
#pragma unroll
      for (int t = 0; t < TILE; ++t) {
        float p = partner<lm>(y[t][r]);
        y[t][r] = cs[r].x * y[t][r] + cs[r].y * p;
      }
    }
  }
}

// ---------------------------------------------------------------------------
// Main: one wave per 4 rows. Layout: lane = i[7:2], reg = {i[9:8], i[1:0]}
//  -> bits 9,8,1,0 are register-local pairs; bits 7..2 are cross-lane.
//  -> float4 global loads/stores (16 B/lane).
// y = 64 VGPR; total demand ~110 -> fits the 128-reg / 4-waves-per-EU budget
// the allocator insists on (R2/R3 evidence), so zero scratch.
// ---------------------------------------------------------------------------
__global__ __launch_bounds__(256)
void bfly_main(const float* __restrict__ X,
               const float2* __restrict__ tab,
               float* __restrict__ out) {
  const int lane = threadIdx.x & 63;
  const int wid  = blockIdx.x * (blockDim.x >> 6) + (threadIdx.x >> 6);
  const long base = (long)wid * TILE * WIDTH;

  float y[TILE][16];

  // ---- load 4 rows, 4 float4 each ----
  const float* xp = X + base;
#pragma unroll
  for (int t = 0; t < TILE; ++t) {
#pragma unroll
    for (int k = 0; k < 4; ++k) {
      float4 v = *reinterpret_cast<const float4*>(
          xp + t * WIDTH + k * 256 + lane * 4);
      y[t][k * 4 + 0] = v.x;
      y[t][k * 4 + 1] = v.y;
      y[t][k * 4 + 2] = v.z;
      y[t][k * 4 + 3] = v.w;
    }
  }

  // ---- 20 layers, each a separate instantiation with constexpr constants --
  bfly_layer<0>(y, tab, lane);
  bfly_layer<1>(y, tab, lane);
  bfly_layer<2>(y, tab, lane);
  bfly_layer<3>(y, tab, lane);
  bfly_layer<4>(y, tab, lane);
  bfly_layer<5>(y, tab, lane);
  bfly_layer<6>(y, tab, lane);
  bfly_layer<7>(y, tab, lane);
  bfly_layer<8>(y, tab, lane);
  bfly_layer<9>(y, tab, lane);
  bfly_layer<10>(y, tab, lane);
  bfly_layer<11>(y, tab, lane);
  bfly_layer<12>(y, tab, lane);
  bfly_layer<13>(y, tab, lane);
  bfly_layer<14>(y, tab, lane);
  bfly_layer<15>(y, tab, lane);
  bfly_layer<16>(y, tab, lane);
  bfly_layer<17>(y, tab, lane);
  bfly_layer<18>(y, tab, lane);
  bfly_layer<19>(y, tab, lane);

  // ---- store (y_20 == x_20: no permutation) ----
  float* op = out + base;
#pragma unroll
  for (int t = 0; t < TILE; ++t) {
#pragma unroll
    for (int k = 0; k < 4; ++k) {
      float4 v;
      v.x = y[t][k * 4 + 0];
      v.y = y[t][k * 4 + 1];
      v.z = y[t][k * 4 + 2];
      v.w = y[t][k * 4 + 3];
      *reinterpret_cast<float4*>(op + t * WIDTH + k * 256 + lane * 4) = v;
    }
  }
}

extern "C" void kernel_launch(void* const* d_in, const int* in_sizes, int n_in,
                              void* d_out, int out_size, void* d_ws, size_t ws_size,
                              hipStream_t stream) {
  const float* X      = (const float*)d_in[0];
  const float* params = (const float*)d_in[1];
  float* out          = (float*)d_out;
  float2* tab         = (float2*)d_ws;   // needs 160 KiB of ws

  // 1) bake coefficient table (re-done every call; ws is re-poisoned)
  bfly_setup<<<(DEPTH * 16 * 64 + 255) / 256, 256, 0, stream>>>(params, tab);

  // 2) butterfly: 32768 rows / 4 rows-per-wave = 8192 waves = 2048 blocks
  bfly_main<<<(NROWS / TILE) / 4, 256, 0, stream>>>(X, tab, out);
}

// Round 16
// 257.808 us; speedup vs baseline: 1.9294x; 1.0540x over previous
//
#include <hip/hip_runtime.h>

// OrthogonalButterfly: 20 layers of Givens rotations on pairs (j, j+512)
// followed by a perfect shuffle. In the substituted domain y_d[i] =
// x_d[rotl_d(i)] the network is an in-place butterfly (layer d pairs bit
// b=9-(d%10); y_20 == x_20, no physical permutation).
//
// R1: layer constants must be compile-time (template<int d>) else y spills.
// R2/R3: allocator caps at 128 VGPR; TILE=8 spilled 0.5-0.8 GB. TILE=4 fits.
// R11 (TILE=4, measured): 117.8 us main, VGPR=112 no spills, WRITE=128MiB
// exact, VALUBusy 30%, Occ 21%. Latency-bound on the 320x8B tab loads/thread
// (1.31 GB L2 traffic). This round: pack coefficients as float4 (2 pairs) and
// store only ACTIVE pairs for reg-local layers -> 128 loads/thread, 655 MB.
// R12-R15: GPU acquisition timeouts — identical kernel resubmitted, untested.

#define WIDTH   1024
#define DEPTH   20
#define NROWS   32768
#define TILE    4          // rows per wave, held in registers (4*16 VGPR)

// ---- shared layout helpers (host of truth: these four functions) ----------
// layer kind: reg-local when b=9-(d%10) in {9,8,1,0}  <=>  d%10 in {0,1,8,9}
__host__ __device__ constexpr int slots_in(int dm) {       // float4 slots/layer
  return (dm < 2 || dm >= 8) ? 4 : 8;
}
__host__ __device__ constexpr int prefix_slots(int dm) {
  int s = 0;
  for (int i = 0; i < dm; ++i) s += slots_in(i);
  return s;
}
__host__ __device__ constexpr int slot_base(int d) {       // 64 slots / decade
  return (d / 10) * 64 + prefix_slots(d % 10);
}
// k-th active r for reg-local mask rm (insert 0 at bit log2(rm))
__host__ __device__ constexpr int act_r(int k, int rm) {
  return ((k & ~(rm - 1)) << 1) | (k & (rm - 1));
}
// total float4 slots: 2 decades * 64 = 128; table = 128*64*16B = 128 KiB

// ---------------------------------------------------------------------------
// Setup: bake tab4[(slot_base(d)+slot)*64 + lane] = (c0,s0,c1,s1) for the
// slot's two (r) entries, sign-folded per element exactly as R2-R11 (proven).
// Reg-local layers store only the 8 active r's (bit-clear side).
// ---------------------------------------------------------------------------
__global__ void bfly_setup(const float* __restrict__ params,
                           float4* __restrict__ tab4) {
  int tid = blockIdx.x * blockDim.x + threadIdx.x;
  if (tid >= 128 * 64) return;
  int L     = tid & 63;
  int gslot = tid >> 6;          // 0..127
  int dec   = gslot >> 6;        // decade
  int rem   = gslot & 63;
  int dm, slot;
  if (rem < 8)       { dm = rem >> 2;            slot = rem & 3; }
  else if (rem < 56) { dm = 2 + (rem - 8) / 8;   slot = (rem - 8) & 7; }
  else               { dm = 8 + (rem - 56) / 4;  slot = (rem - 56) & 3; }
  int d   = dec * 10 + dm;
  int rot = dm;
  int b   = 9 - rot;
  int m   = 1 << b;
  bool reglocal = (dm < 2 || dm >= 8);
  int rm = (b == 9) ? 8 : (b == 8) ? 4 : (b == 1) ? 2 : 1;  // only if reglocal

  float v[4];
#pragma unroll
  for (int p = 0; p < 2; ++p) {
    int k  = slot * 2 + p;
    int rr = reglocal ? act_r(k, rm) : k;
    int i  = ((rr >> 2) << 8) | (L << 2) | (rr & 3);
    int i0 = i & ~m;
    int j  = rot ? (((i0 << rot) | (i0 >> (10 - rot))) & 1023) : i0;
    float theta = params[j * DEPTH + d];
    float c = cosf(theta);
    float s = sinf(theta);
    if (i & m) s = -s;
    v[2 * p]     = c;
    v[2 * p + 1] = s;
  }
  tab4[gslot * 64 + L] = make_float4(v[0], v[1], v[2], v[3]);
}

// ---------------------------------------------------------------------------
// Cross-lane partner fetch, compile-time mask (all verified R3/R11).
// ---------------------------------------------------------------------------
template <int lm>
__device__ __forceinline__ float partner(float x) {
  if constexpr (lm == 1) {
    return __int_as_float(__builtin_amdgcn_update_dpp(
        0, __float_as_int(x), 0xB1, 0xF, 0xF, true));      // quad [1,0,3,2]
  } else if constexpr (lm == 2) {
    return __int_as_float(__builtin_amdgcn_update_dpp(
        0, __float_as_int(x), 0x4E, 0xF, 0xF, true));      // quad [2,3,0,1]
  } else if constexpr (lm == 8) {
    return __int_as_float(__builtin_amdgcn_update_dpp(
        0, __float_as_int(x), 0x128, 0xF, 0xF, true));     // row_ror:8 == xor8
  } else if constexpr (lm == 4) {
    return __int_as_float(__builtin_amdgcn_ds_swizzle(
        __float_as_int(x), 0x101F));                       // xor4
  } else if constexpr (lm == 16) {
    return __int_as_float(__builtin_amdgcn_ds_swizzle(
        __float_as_int(x), 0x401F));                       // xor16
  } else {
    return __shfl_xor(x, 32, 64);                          // xor32
  }
}

// ---------------------------------------------------------------------------
// One butterfly layer; float4 coefficient loads (2 pairs each).
// ---------------------------------------------------------------------------
template <int d>
__device__ __forceinline__ void bfly_layer(float (&y)[TILE][16],
                                           const float4* __restrict__ tab4,
                                           int lane) {
  constexpr int b  = 9 - (d % 10);
  constexpr int B0 = slot_base(d);

  if constexpr (b >= 8 || b <= 1) {
    constexpr int rm = (b == 9) ? 8 : (b == 8) ? 4 : (b == 1) ? 2 : 1;
#pragma unroll
    for (int q = 0; q < 4; ++q) {
      float4 cs = tab4[(B0 + q) * 64 + lane];
      const int r00 = act_r(2 * q, rm),     r01 = r00 | rm;   // folds at unroll
      const int r10 = act_r(2 * q + 1, rm), r11 = r10 | rm;
#pragma unroll
      for (int t = 0; t < TILE; ++t) {
        float a0 = y[t][r00], a1 = y[t][r01];
        y[t][r00] = cs.x * a0 + cs.y * a1;       // stored (c,+s), bit-clear r
        y[t][r01] = cs.x * a1 - cs.y * a0;       // partner uses (c,-s)
        float b0 = y[t][r10], b1 = y[t][r11];
        y[t][r10] = cs.z * b0 + cs.w * b1;
        y[t][r11] = cs.z * b1 - cs.w * b0;
      }
    }
  } else {
    constexpr int lm = 1 << (b - 2);
#pragma unroll
    for (int q = 0; q < 8; ++q) {
      float4 cs = tab4[(B0 + q) * 64 + lane];
      const int r0 = 2 * q, r1 = 2 * q + 1;
#pragma unroll
      for (int t = 0; t < TILE; ++t) {
        float p0 = partner<lm>(y[t][r0]);
        y[t][r0] = cs.x * y[t][r0] + cs.y * p0;  // s sign-folded per lane
        float p1 = partner<lm>(y[t][r1]);
        y[t][r1] = cs.z * y[t][r1] + cs.w * p1;
      }
    }
  }
}

// ---------------------------------------------------------------------------
// Main: one wave per 4 rows. lane = i[7:2], reg = {i[9:8], i[1:0]}.
// ---------------------------------------------------------------------------
__global__ __launch_bounds__(256)
void bfly_main(const float* __restrict__ X,
               const float4* __restrict__ tab4,
               float* __restrict__ out) {
  const int lane = threadIdx.x & 63;
  const int wid  = blockIdx.x * (blockDim.x >> 6) + (threadIdx.x >> 6);
  const long base = (long)wid * TILE * WIDTH;

  float y[TILE][16];

  const float* xp = X + base;
#pragma unroll
  for (int t = 0; t < TILE; ++t) {
#pragma unroll
    for (int k = 0; k < 4; ++k) {
      float4 v = *reinterpret_cast<const float4*>(
          xp + t * WIDTH + k * 256 + lane * 4);
      y[t][k * 4 + 0] = v.x;
      y[t][k * 4 + 1] = v.y;
      y[t][k * 4 + 2] = v.z;
      y[t][k * 4 + 3] = v.w;
    }
  }

  bfly_layer<0>(y, tab4, lane);
  bfly_layer<1>(y, tab4, lane);
  bfly_layer<2>(y, tab4, lane);
  bfly_layer<3>(y, tab4, lane);
  bfly_layer<4>(y, tab4, lane);
  bfly_layer<5>(y, tab4, lane);
  bfly_layer<6>(y, tab4, lane);
  bfly_layer<7>(y, tab4, lane);
  bfly_layer<8>(y, tab4, lane);
  bfly_layer<9>(y, tab4, lane);
  bfly_layer<10>(y, tab4, lane);
  bfly_layer<11>(y, tab4, lane);
  bfly_layer<12>(y, tab4, lane);
  bfly_layer<13>(y, tab4, lane);
  bfly_layer<14>(y, tab4, lane);
  bfly_layer<15>(y, tab4, lane);
  bfly_layer<16>(y, tab4, lane);
  bfly_layer<17>(y, tab4, lane);
  bfly_layer<18>(y, tab4, lane);
  bfly_layer<19>(y, tab4, lane);

  float* op = out + base;
#pragma unroll
  for (int t = 0; t < TILE; ++t) {
#pragma unroll
    for (int k = 0; k < 4; ++k) {
      float4 v;
      v.x = y[t][k * 4 + 0];
      v.y = y[t][k * 4 + 1];
      v.z = y[t][k * 4 + 2];
      v.w = y[t][k * 4 + 3];
      *reinterpret_cast<float4*>(op + t * WIDTH + k * 256 + lane * 4) = v;
    }
  }
}

extern "C" void kernel_launch(void* const* d_in, const int* in_sizes, int n_in,
                              void* d_out, int out_size, void* d_ws, size_t ws_size,
                              hipStream_t stream) {
  const float* X      = (const float*)d_in[0];
  const float* params = (const float*)d_in[1];
  float* out          = (float*)d_out;
  float4* tab4        = (float4*)d_ws;   // 128 slots * 64 lanes * 16B = 128 KiB

  // 1) bake packed coefficient table (re-done every call; ws re-poisoned)
  bfly_setup<<<(128 * 64 + 255) / 256, 256, 0, stream>>>(params, tab4);

  // 2) butterfly: 32768 rows / 4 rows-per-wave = 8192 waves = 2048 blocks
  bfly_main<<<(NROWS / TILE) / 4, 256, 0, stream>>>(X, tab4, out);
}